// Round 1
// baseline (824.061 us; speedup 1.0000x reference)
//
#include <hip/hip_runtime.h>
#include <math.h>

#define BB 32
#define HH 256
#define WW 256
#define HW (HH*WW)
#define TOT (BB*HW)
#define PAD 2
#define K_BG 0.1f
#define RELAX 5.0f
#define INF_D 1e4f
#define EPS_D 1e-7

__device__ __forceinline__ float sigf(float x) { return 1.0f / (1.0f + expf(-x)); }

// ---------------- init accumulators ----------------
__global__ void k_init(double* sums, int* dminb, int* dmaxb, int* hasfg) {
    int t = threadIdx.x;
    if (t < 2) sums[t] = 0.0;
    if (t < BB) {
        dminb[t] = 0x7f800000;  // +inf bits (d >= 0 so int-bit order == float order)
        dmaxb[t] = 0;           // 0.0f
        hasfg[t] = 0;
    }
}

// ---------------- 5x5 dilation + per-batch has_fg ----------------
__global__ void k_dilate(const float* __restrict__ tg, float* __restrict__ fat,
                         int* __restrict__ hasfg) {
    int idx = blockIdx.x * blockDim.x + threadIdx.x;
    if (idx >= TOT) return;
    int b = idx / HW;
    int r = (idx / WW) % HH;
    int c = idx % WW;
    const float* base = tg + b * HW;
    int r0 = max(r - PAD, 0), r1 = min(r + PAD, HH - 1);
    int c0 = max(c - PAD, 0), c1 = min(c + PAD, WW - 1);
    float m = 0.0f;  // targets >= 0, window non-empty -> same as -inf init
    for (int i = r0; i <= r1; ++i) {
        const float* row = base + i * WW;
        for (int j = c0; j <= c1; ++j) m = fmaxf(m, row[j]);
    }
    fat[idx] = m;
    if (tg[idx] != 0.0f) atomicOr(&hasfg[b], 1);
}

// ---------------- vertical distance to nearest zero (clamped at INF_D) ----------------
// one thread per (b, column); coalesced across columns
__global__ void k_vdist(const float* __restrict__ fat, float* __restrict__ g) {
    int idx = blockIdx.x * blockDim.x + threadIdx.x;
    if (idx >= BB * WW) return;
    int b = idx / WW, c = idx % WW;
    const float* f = fat + b * HW + c;
    float* gg = g + b * HW + c;
    float carry = INF_D;
    for (int i = 0; i < HH; ++i) {
        float z = f[i * WW];
        float d = (z == 0.0f) ? 0.0f : fminf(carry + 1.0f, INF_D);
        carry = d;
        gg[i * WW] = d;
    }
    carry = INF_D;
    for (int i = HH - 1; i >= 0; --i) {
        float z = f[i * WW];
        float d = (z == 0.0f) ? 0.0f : fminf(carry + 1.0f, INF_D);
        carry = d;
        gg[i * WW] = fminf(gg[i * WW], d);
    }
}

// ---------------- horizontal min-plus EDT (in-place g -> d) + per-batch min/max(d) ----------------
// one block (256 threads) per row
__global__ void k_edt(float* __restrict__ g, int* __restrict__ dminb, int* __restrict__ dmaxb) {
    __shared__ float g2[WW];
    __shared__ float smn[4], smx[4];
    int row = blockIdx.x;  // 0 .. BB*HH-1
    float* grow = g + (long)row * WW;
    int j = threadIdx.x;
    float gv = grow[j];
    g2[j] = gv * gv;
    __syncthreads();
    float best = 3.4e38f;
    #pragma unroll 8
    for (int k = 0; k < WW; ++k) {
        float off = (float)(j - k);
        best = fminf(best, fmaf(off, off, g2[k]));
    }
    float d = sqrtf(best);
    grow[j] = d;

    float mn = d, mx = d;
    for (int off = 32; off > 0; off >>= 1) {
        mn = fminf(mn, __shfl_down(mn, off, 64));
        mx = fmaxf(mx, __shfl_down(mx, off, 64));
    }
    int wid = threadIdx.x >> 6, lane = threadIdx.x & 63;
    if (lane == 0) { smn[wid] = mn; smx[wid] = mx; }
    __syncthreads();
    if (threadIdx.x == 0) {
        float a = smn[0], bmx = smx[0];
        for (int i = 1; i < 4; ++i) { a = fminf(a, smn[i]); bmx = fmaxf(bmx, smx[i]); }
        int b = row / HH;
        atomicMin(&dminb[b], __float_as_int(a));
        atomicMax(&dmaxb[b], __float_as_int(bmx));
    }
}

// ---------------- fused distance-map + dice partial sums ----------------
__global__ void k_final(const float* __restrict__ preds, const float* __restrict__ tg,
                        const float* __restrict__ fat, const float* __restrict__ d,
                        const int* __restrict__ dminb, const int* __restrict__ dmaxb,
                        const int* __restrict__ hasfg, double* __restrict__ sums) {
    int idx = blockIdx.x * blockDim.x + threadIdx.x;
    float inter = 0.0f, card = 0.0f;
    if (idx < TOT) {
        int b = idx / HW;
        float t = tg[idx];
        float dm;
        if (hasfg[b]) {
            float smin = sigf(__int_as_float(dminb[b]) / RELAX);
            float smax = sigf(__int_as_float(dmaxb[b]) / RELAX);
            float mx = smax - smin;
            float denom = (mx > 0.0f) ? mx : 1.0f;
            float soft = (sigf(d[idx] / RELAX) - smin) / denom;
            dm = soft + (1.0f - fat[idx]) * K_BG;
        } else {
            dm = 1.0f - t;
        }
        float pw = sigf(preds[idx]) * dm;
        inter = pw * t;
        card = pw + t;
    }
    for (int off = 32; off > 0; off >>= 1) {
        inter += __shfl_down(inter, off, 64);
        card  += __shfl_down(card,  off, 64);
    }
    __shared__ float si[4], sc[4];
    int wid = threadIdx.x >> 6, lane = threadIdx.x & 63;
    if (lane == 0) { si[wid] = inter; sc[wid] = card; }
    __syncthreads();
    if (threadIdx.x == 0) {
        float ti = 0.0f, tc = 0.0f;
        for (int i = 0; i < 4; ++i) { ti += si[i]; tc += sc[i]; }
        atomicAdd(&sums[0], (double)ti);
        atomicAdd(&sums[1], (double)tc);
    }
}

// ---------------- finalize scalar ----------------
__global__ void k_fin(const double* __restrict__ sums, const int* __restrict__ hasfg,
                      float* __restrict__ out) {
    double inter = sums[0], card = sums[1];
    double dice = (2.0 * inter) / fmax(card, EPS_D);
    int any = 0;
    for (int b = 0; b < BB; ++b) any |= hasfg[b];
    out[0] = any ? (float)(1.0 - dice) : 0.0f;
}

extern "C" void kernel_launch(void* const* d_in, const int* in_sizes, int n_in,
                              void* d_out, int out_size, void* d_ws, size_t ws_size,
                              hipStream_t stream) {
    const float* preds = (const float*)d_in[0];
    const float* tg    = (const float*)d_in[1];
    float* out = (float*)d_out;

    float* fat = (float*)d_ws;
    float* g   = fat + TOT;                 // reused in-place as d after k_edt
    double* sums = (double*)(g + TOT);      // 16 MB offset, 8B aligned
    int* dminb = (int*)(sums + 2);
    int* dmaxb = dminb + BB;
    int* hasfg = dmaxb + BB;

    hipLaunchKernelGGL(k_init, dim3(1), dim3(64), 0, stream, sums, dminb, dmaxb, hasfg);
    int nblk = (TOT + 255) / 256;
    hipLaunchKernelGGL(k_dilate, dim3(nblk), dim3(256), 0, stream, tg, fat, hasfg);
    hipLaunchKernelGGL(k_vdist, dim3((BB * WW + 255) / 256), dim3(256), 0, stream, fat, g);
    hipLaunchKernelGGL(k_edt, dim3(BB * HH), dim3(WW), 0, stream, g, dminb, dmaxb);
    hipLaunchKernelGGL(k_final, dim3(nblk), dim3(256), 0, stream, preds, tg, fat, g,
                       dminb, dmaxb, hasfg, sums);
    hipLaunchKernelGGL(k_fin, dim3(1), dim3(1), 0, stream, sums, hasfg, out);
}

// Round 2
// 345.177 us; speedup vs baseline: 2.3874x; 2.3874x over previous
//
#include <hip/hip_runtime.h>
#include <math.h>

#define BB 32
#define HH 256
#define WW 256
#define HW (HH*WW)
#define TOT (BB*HW)
#define PAD 2
#define K_BG 0.1f
#define RELAX 5.0f
#define INF_D 1e4f
#define EPS_D 1e-7
#define NBF 2048          // k_final blocks (grid-stride x4)

__device__ __forceinline__ float sigf(float x) { return 1.0f / (1.0f + expf(-x)); }

// ---------------- init accumulators ----------------
__global__ void k_init(int* dminb, int* dmaxb, int* hasfg) {
    int t = threadIdx.x;
    if (t < BB) {
        dminb[t] = 0x7f800000;  // +inf bits (d >= 0 so int-bit order == float order)
        dmaxb[t] = 0;           // 0.0f
        hasfg[t] = 0;
    }
}

// ---------------- horizontal 1x5 max + per-batch has_fg ----------------
__global__ void k_dil_h(const float* __restrict__ tg, float* __restrict__ tmp,
                        int* __restrict__ hasfg) {
    int idx = blockIdx.x * blockDim.x + threadIdx.x;
    int c = idx % WW;
    const float* row = tg + (idx - c);
    int c0 = max(c - PAD, 0), c1 = min(c + PAD, WW - 1);
    float m = 0.0f;
    for (int j = c0; j <= c1; ++j) m = fmaxf(m, row[j]);
    tmp[idx] = m;

    // block-level has-foreground flag (block lies within one batch: 256 | HW)
    bool f = row[c] != 0.0f;
    unsigned long long bal = __ballot(f);
    __shared__ int flag;
    if (threadIdx.x == 0) flag = 0;
    __syncthreads();
    if ((threadIdx.x & 63) == 0 && bal != 0ULL) flag = 1;   // benign same-value race
    __syncthreads();
    if (threadIdx.x == 0 && flag) atomicOr(&hasfg[idx / HW], 1);
}

// ---------------- vertical 5x1 max ----------------
__global__ void k_dil_v(const float* __restrict__ tmp, float* __restrict__ fat) {
    int idx = blockIdx.x * blockDim.x + threadIdx.x;
    int b = idx / HW;
    int r = (idx / WW) % HH;
    int c = idx % WW;
    const float* col = tmp + b * HW + c;
    int r0 = max(r - PAD, 0), r1 = min(r + PAD, HH - 1);
    float m = 0.0f;
    for (int i = r0; i <= r1; ++i) m = fmaxf(m, col[i * WW]);
    fat[idx] = m;
}

// ---------------- vertical distance to nearest zero (clamped at INF_D) ----------------
// one thread per (b, column); coalesced across columns
__global__ void k_vdist(const float* __restrict__ fat, float* __restrict__ g) {
    int idx = blockIdx.x * blockDim.x + threadIdx.x;
    if (idx >= BB * WW) return;
    int b = idx / WW, c = idx % WW;
    const float* f = fat + b * HW + c;
    float* gg = g + b * HW + c;
    float carry = INF_D;
    for (int i = 0; i < HH; ++i) {
        float z = f[i * WW];
        float d = (z == 0.0f) ? 0.0f : fminf(carry + 1.0f, INF_D);
        carry = d;
        gg[i * WW] = d;
    }
    carry = INF_D;
    for (int i = HH - 1; i >= 0; --i) {
        float z = f[i * WW];
        float d = (z == 0.0f) ? 0.0f : fminf(carry + 1.0f, INF_D);
        carry = d;
        gg[i * WW] = fminf(gg[i * WW], d);
    }
}

// ---------------- horizontal min-plus EDT (in-place g -> d) + per-batch min/max(d) ----------------
// one block (256 threads) per row
__global__ void k_edt(float* __restrict__ g, int* __restrict__ dminb, int* __restrict__ dmaxb) {
    __shared__ float g2[WW];
    __shared__ float smn[4], smx[4];
    int row = blockIdx.x;  // 0 .. BB*HH-1
    float* grow = g + (long)row * WW;
    int j = threadIdx.x;
    float gv = grow[j];
    g2[j] = gv * gv;
    __syncthreads();
    float best = 3.4e38f;
    #pragma unroll 8
    for (int k = 0; k < WW; ++k) {
        float off = (float)(j - k);
        best = fminf(best, fmaf(off, off, g2[k]));
    }
    float d = sqrtf(best);
    grow[j] = d;

    float mn = d, mx = d;
    for (int off = 32; off > 0; off >>= 1) {
        mn = fminf(mn, __shfl_down(mn, off, 64));
        mx = fmaxf(mx, __shfl_down(mx, off, 64));
    }
    int wid = threadIdx.x >> 6, lane = threadIdx.x & 63;
    if (lane == 0) { smn[wid] = mn; smx[wid] = mx; }
    __syncthreads();
    if (threadIdx.x == 0) {
        float a = smn[0], bmx = smx[0];
        for (int i = 1; i < 4; ++i) { a = fminf(a, smn[i]); bmx = fmaxf(bmx, smx[i]); }
        int b = row / HH;
        atomicMin(&dminb[b], __float_as_int(a));
        atomicMax(&dmaxb[b], __float_as_int(bmx));
    }
}

// ---------------- fused distance-map + dice partial sums (no atomics) ----------------
__global__ void k_final(const float* __restrict__ preds, const float* __restrict__ tg,
                        const float* __restrict__ fat, const float* __restrict__ d,
                        const int* __restrict__ dminb, const int* __restrict__ dmaxb,
                        const int* __restrict__ hasfg, float2* __restrict__ part) {
    int tid = blockIdx.x * blockDim.x + threadIdx.x;
    const int stride = NBF * 256;
    float inter = 0.0f, card = 0.0f;
    #pragma unroll
    for (int it = 0; it < TOT / stride; ++it) {
        int idx = tid + it * stride;
        int b = idx / HW;
        float t = tg[idx];
        float dm;
        if (hasfg[b]) {
            float smin = sigf(__int_as_float(dminb[b]) / RELAX);
            float smax = sigf(__int_as_float(dmaxb[b]) / RELAX);
            float mx = smax - smin;
            float denom = (mx > 0.0f) ? mx : 1.0f;
            float soft = (sigf(d[idx] / RELAX) - smin) / denom;
            dm = soft + (1.0f - fat[idx]) * K_BG;
        } else {
            dm = 1.0f - t;
        }
        float pw = sigf(preds[idx]) * dm;
        inter += pw * t;
        card += pw + t;
    }
    for (int off = 32; off > 0; off >>= 1) {
        inter += __shfl_down(inter, off, 64);
        card  += __shfl_down(card,  off, 64);
    }
    __shared__ float si[4], sc[4];
    int wid = threadIdx.x >> 6, lane = threadIdx.x & 63;
    if (lane == 0) { si[wid] = inter; sc[wid] = card; }
    __syncthreads();
    if (threadIdx.x == 0) {
        float ti = 0.0f, tc = 0.0f;
        for (int i = 0; i < 4; ++i) { ti += si[i]; tc += sc[i]; }
        part[blockIdx.x] = make_float2(ti, tc);
    }
}

// ---------------- finalize scalar: reduce partials in double ----------------
__global__ void k_fin(const float2* __restrict__ part, const int* __restrict__ hasfg,
                      float* __restrict__ out) {
    int t = threadIdx.x;
    double di = 0.0, dc = 0.0;
    for (int i = t; i < NBF; i += 256) { di += (double)part[i].x; dc += (double)part[i].y; }
    for (int off = 32; off > 0; off >>= 1) {
        di += __shfl_down(di, off, 64);
        dc += __shfl_down(dc, off, 64);
    }
    __shared__ double sdi[4], sdc[4];
    int wid = t >> 6, lane = t & 63;
    if (lane == 0) { sdi[wid] = di; sdc[wid] = dc; }
    __syncthreads();
    if (t == 0) {
        double I = 0.0, C = 0.0;
        for (int i = 0; i < 4; ++i) { I += sdi[i]; C += sdc[i]; }
        int any = 0;
        for (int b = 0; b < BB; ++b) any |= hasfg[b];
        double dice = 2.0 * I / fmax(C, (double)EPS_D);
        out[0] = any ? (float)(1.0 - dice) : 0.0f;
    }
}

extern "C" void kernel_launch(void* const* d_in, const int* in_sizes, int n_in,
                              void* d_out, int out_size, void* d_ws, size_t ws_size,
                              hipStream_t stream) {
    const float* preds = (const float*)d_in[0];
    const float* tg    = (const float*)d_in[1];
    float* out = (float*)d_out;

    float* fat = (float*)d_ws;
    float* g   = fat + TOT;                 // also used as tmp for separable dilate
    float2* part = (float2*)(g + TOT);
    int* dminb = (int*)(part + NBF);
    int* dmaxb = dminb + BB;
    int* hasfg = dmaxb + BB;

    int nblk = TOT / 256;
    hipLaunchKernelGGL(k_init, dim3(1), dim3(64), 0, stream, dminb, dmaxb, hasfg);
    hipLaunchKernelGGL(k_dil_h, dim3(nblk), dim3(256), 0, stream, tg, g, hasfg);
    hipLaunchKernelGGL(k_dil_v, dim3(nblk), dim3(256), 0, stream, g, fat);
    hipLaunchKernelGGL(k_vdist, dim3((BB * WW + 255) / 256), dim3(256), 0, stream, fat, g);
    hipLaunchKernelGGL(k_edt, dim3(BB * HH), dim3(WW), 0, stream, g, dminb, dmaxb);
    hipLaunchKernelGGL(k_final, dim3(NBF), dim3(256), 0, stream, preds, tg, fat, g,
                       dminb, dmaxb, hasfg, part);
    hipLaunchKernelGGL(k_fin, dim3(1), dim3(256), 0, stream, part, hasfg, out);
}

// Round 3
// 154.323 us; speedup vs baseline: 5.3398x; 2.2367x over previous
//
#include <hip/hip_runtime.h>
#include <math.h>

#define BB 32
#define HH 256
#define WW 256
#define HW (HH*WW)
#define TOT (BB*HW)
#define RB 16            // rows per dilate block
#define K_BG 0.1f
#define RELAX 5.0f
#define EPS_D 1e-7
#define NBF 2048         // k_final blocks (grid-stride x4)

__device__ __forceinline__ float sigf(float x) { return 1.0f / (1.0f + expf(-x)); }

// ---------------- fused 5x5 dilation (separable, LDS) ----------------
// zero-padding == edge-clamp here since targets >= 0
__global__ void k_dilate(const float* __restrict__ tg, float* __restrict__ fat) {
    __shared__ float raw[RB + 4][WW];
    __shared__ float hm[RB + 4][WW];
    const int nb = HH / RB;
    int b = blockIdx.x / nb, band = blockIdx.x % nb;
    int r0 = band * RB, j = threadIdx.x;
    const float* img = tg + b * HW;
    for (int rr = 0; rr < RB + 4; ++rr) {
        int rg = r0 + rr - 2;
        raw[rr][j] = (rg >= 0 && rg < HH) ? img[rg * WW + j] : 0.0f;
    }
    __syncthreads();
    int c0 = max(j - 2, 0), c1 = min(j + 2, WW - 1);
    for (int rr = 0; rr < RB + 4; ++rr) {
        float m = 0.0f;
        for (int c = c0; c <= c1; ++c) m = fmaxf(m, raw[rr][c]);
        hm[rr][j] = m;
    }
    __syncthreads();
    float* out = fat + b * HW + r0 * WW + j;
    for (int rr = 0; rr < RB; ++rr) {
        float m = hm[rr][j];
        #pragma unroll
        for (int k = 1; k < 5; ++k) m = fmaxf(m, hm[rr + k][j]);
        out[rr * WW] = m;
    }
}

// ---------------- exact EDT via expanding Chebyshev rings ----------------
// d[i][j] = distance to nearest zero of fat (2D); == separable vdist+minplus.
// No zero anywhere -> best stays 1e8 -> sqrt = 1e4 == reference INF clamp.
__global__ void k_ring(const float* __restrict__ fat, float* __restrict__ d,
                       float* __restrict__ rowmn, float* __restrict__ rowmx) {
    int row = blockIdx.x;              // 0 .. BB*HH-1
    int b = row >> 8, i = row & 255, j = threadIdx.x;
    const float* img = fat + b * HW;
    float best = (img[i * WW + j] == 0.0f) ? 0.0f : 1e8f;
    for (int r = 1; r < 256; ++r) {
        if ((float)(r * r) >= best) break;
        int it = i - r, ib = i + r;
        bool vt = (it >= 0), vb = (ib < HH);
        if (vt || vb) {
            int cc0 = max(j - r, 0), cc1 = min(j + r, WW - 1);
            for (int c = cc0; c <= cc1; ++c) {
                float dd = (float)(r * r + (c - j) * (c - j));
                if (vt && img[it * WW + c] == 0.0f) best = fminf(best, dd);
                if (vb && img[ib * WW + c] == 0.0f) best = fminf(best, dd);
            }
        }
        int cl = j - r, cr = j + r;
        bool vl = (cl >= 0), vr = (cr < WW);
        if (vl || vr) {
            int t0 = max(i - (r - 1), 0), t1 = min(i + (r - 1), HH - 1);
            for (int t = t0; t <= t1; ++t) {
                float dd = (float)(r * r + (t - i) * (t - i));
                if (vl && img[t * WW + cl] == 0.0f) best = fminf(best, dd);
                if (vr && img[t * WW + cr] == 0.0f) best = fminf(best, dd);
            }
        }
    }
    float dv = sqrtf(best);
    d[(long)row * WW + j] = dv;        // row*WW == b*HW + i*WW

    float mn = dv, mx = dv;
    for (int off = 32; off > 0; off >>= 1) {
        mn = fminf(mn, __shfl_down(mn, off, 64));
        mx = fmaxf(mx, __shfl_down(mx, off, 64));
    }
    __shared__ float smn[4], smx[4];
    int wid = threadIdx.x >> 6, lane = threadIdx.x & 63;
    if (lane == 0) { smn[wid] = mn; smx[wid] = mx; }
    __syncthreads();
    if (threadIdx.x == 0) {
        float a = smn[0], z = smx[0];
        for (int k = 1; k < 4; ++k) { a = fminf(a, smn[k]); z = fmaxf(z, smx[k]); }
        rowmn[row] = a; rowmx[row] = z;
    }
}

// ---------------- per-batch min/max of d (no atomics) ----------------
__global__ void k_mnmx(const float* __restrict__ rowmn, const float* __restrict__ rowmx,
                       float* __restrict__ dmnb, float* __restrict__ dmxb) {
    int b = blockIdx.x, t = threadIdx.x;
    float mn = rowmn[b * HH + t], mx = rowmx[b * HH + t];
    for (int off = 32; off > 0; off >>= 1) {
        mn = fminf(mn, __shfl_down(mn, off, 64));
        mx = fmaxf(mx, __shfl_down(mx, off, 64));
    }
    __shared__ float smn[4], smx[4];
    int wid = t >> 6, lane = t & 63;
    if (lane == 0) { smn[wid] = mn; smx[wid] = mx; }
    __syncthreads();
    if (t == 0) {
        float a = smn[0], z = smx[0];
        for (int k = 1; k < 4; ++k) { a = fminf(a, smn[k]); z = fmaxf(z, smx[k]); }
        dmnb[b] = a; dmxb[b] = z;
    }
}

// ---------------- fused distance-map + dice partial sums (no atomics) ----------------
__global__ void k_final(const float* __restrict__ preds, const float* __restrict__ tg,
                        const float* __restrict__ fat, const float* __restrict__ d,
                        const float* __restrict__ dmnb, const float* __restrict__ dmxb,
                        float2* __restrict__ part) {
    int tid = blockIdx.x * blockDim.x + threadIdx.x;
    const int stride = NBF * 256;
    float inter = 0.0f, card = 0.0f;
    #pragma unroll
    for (int it = 0; it < TOT / stride; ++it) {
        int idx = tid + it * stride;
        int b = idx / HW;
        float t = tg[idx];
        float dmx = dmxb[b];
        float dm;
        if (dmx > 0.0f) {                       // has foreground
            float smin = sigf(dmnb[b] / RELAX);
            float smax = sigf(dmx / RELAX);
            float mx = smax - smin;
            float denom = (mx > 0.0f) ? mx : 1.0f;
            float soft = (sigf(d[idx] / RELAX) - smin) / denom;
            dm = soft + (1.0f - fat[idx]) * K_BG;
        } else {
            dm = 1.0f - t;
        }
        float pw = sigf(preds[idx]) * dm;
        inter += pw * t;
        card += pw + t;
    }
    for (int off = 32; off > 0; off >>= 1) {
        inter += __shfl_down(inter, off, 64);
        card  += __shfl_down(card,  off, 64);
    }
    __shared__ float si[4], sc[4];
    int wid = threadIdx.x >> 6, lane = threadIdx.x & 63;
    if (lane == 0) { si[wid] = inter; sc[wid] = card; }
    __syncthreads();
    if (threadIdx.x == 0) {
        float ti = 0.0f, tc = 0.0f;
        for (int i = 0; i < 4; ++i) { ti += si[i]; tc += sc[i]; }
        part[blockIdx.x] = make_float2(ti, tc);
    }
}

// ---------------- finalize scalar: reduce partials in double ----------------
__global__ void k_fin(const float2* __restrict__ part, const float* __restrict__ dmxb,
                      float* __restrict__ out) {
    int t = threadIdx.x;
    double di = 0.0, dc = 0.0;
    for (int i = t; i < NBF; i += 256) { di += (double)part[i].x; dc += (double)part[i].y; }
    for (int off = 32; off > 0; off >>= 1) {
        di += __shfl_down(di, off, 64);
        dc += __shfl_down(dc, off, 64);
    }
    __shared__ double sdi[4], sdc[4];
    int wid = t >> 6, lane = t & 63;
    if (lane == 0) { sdi[wid] = di; sdc[wid] = dc; }
    __syncthreads();
    if (t == 0) {
        double I = 0.0, C = 0.0;
        for (int i = 0; i < 4; ++i) { I += sdi[i]; C += sdc[i]; }
        int any = 0;
        for (int b = 0; b < BB; ++b) any |= (dmxb[b] > 0.0f);
        double dice = 2.0 * I / fmax(C, (double)EPS_D);
        out[0] = any ? (float)(1.0 - dice) : 0.0f;
    }
}

extern "C" void kernel_launch(void* const* d_in, const int* in_sizes, int n_in,
                              void* d_out, int out_size, void* d_ws, size_t ws_size,
                              hipStream_t stream) {
    const float* preds = (const float*)d_in[0];
    const float* tg    = (const float*)d_in[1];
    float* out = (float*)d_out;

    float* fat = (float*)d_ws;
    float* d   = fat + TOT;
    float2* part = (float2*)(d + TOT);
    float* rowmn = (float*)(part + NBF);
    float* rowmx = rowmn + BB * HH;
    float* dmnb  = rowmx + BB * HH;
    float* dmxb  = dmnb + BB;

    hipLaunchKernelGGL(k_dilate, dim3(BB * (HH / RB)), dim3(WW), 0, stream, tg, fat);
    hipLaunchKernelGGL(k_ring, dim3(BB * HH), dim3(WW), 0, stream, fat, d, rowmn, rowmx);
    hipLaunchKernelGGL(k_mnmx, dim3(BB), dim3(HH), 0, stream, rowmn, rowmx, dmnb, dmxb);
    hipLaunchKernelGGL(k_final, dim3(NBF), dim3(256), 0, stream, preds, tg, fat, d,
                       dmnb, dmxb, part);
    hipLaunchKernelGGL(k_fin, dim3(1), dim3(256), 0, stream, part, dmxb, out);
}